// Round 5
// baseline (81.799 us; speedup 1.0000x reference)
//
#include <hip/hip_runtime.h>

// LightConv: B=8, T=1024, H=8, S=64, K=31, C=512 (all fp32)
// out[b,t,h*S+s] = sum_k softmax_k(filters[b,t,h,:])[k] * x[b, t+k-15, h*S+s] + bias[h*S+s]
//
// Persistent blocks: 512 blocks x 2 tiles, double-buffered LDS. Tile i+1's
// global->LDS DMA + filter register loads are issued AFTER tile i's barrier,
// so they remain in flight across tile i's compute and are drained only at
// the next barrier (prefetch the 2-barrier structure can't otherwise express).

#define TDIM 1024
#define HH 8
#define SS 64
#define KK 31
#define CC 512
#define HK 248
#define TTILE 64
#define WIN 96
#define PAD 15
#define WSTRIDE 36
#define NBLK 512

__global__ __launch_bounds__(256, 2)
void lightconv_kernel(const float* __restrict__ xg,
                      const float* __restrict__ fg,
                      const float* __restrict__ bg,
                      float* __restrict__ og)
{
    __shared__ float xs[2][WIN * SS];          // 2 x 24576 B
    __shared__ float ws[2][TTILE * WSTRIDE];   // 2 x 9216 B

    const int tid = threadIdx.x;

    // both tiles of this block share tx and h; only b differs (+4)
    const int tx = blockIdx.x & 15;
    const int h  = (blockIdx.x >> 4) & 7;
    const int b0 = blockIdx.x >> 7;            // 0..3
    const int t0 = tx * TTILE;

    // softmax-lane decode: 4 threads per t-row
    const int frow  = tid >> 2;                // 0..63
    const int fbase = (tid & 3) * 8;           // taps fbase..fbase+7

    // compute-lane decode: 4 t x 4 ch per thread
    const int sq = (tid & 15) << 2;
    const int tb = (tid >> 4) << 2;

    const bool interior = (tx != 0) && (tx != 15);

    auto load_filters = [&](int b, float* dst) {
        const float* fp = fg + (size_t)(b * TDIM + t0 + frow) * HK + h * KK + fbase;
        #pragma unroll
        for (int j = 0; j < 8; ++j)
            dst[j] = (fbase + j < KK) ? fp[j] : -1e30f;
    };

    auto stage = [&](int b, int buf) {
        const float* xb = xg + ((size_t)b * TDIM) * CC + h * SS;
        if (interior) {
            #pragma unroll
            for (int i = 0; i < 6; ++i) {
                int f  = tid + i * 256;        // quad 0..1535
                int r  = f >> 4;               // row 0..95
                int c4 = (f & 15) << 2;        // ch 0..60
                const float* gp = xb + (size_t)(t0 - PAD + r) * CC + c4;
                __builtin_amdgcn_global_load_lds(
                    (const __attribute__((address_space(1))) void*)gp,
                    (__attribute__((address_space(3))) void*)&xs[buf][f << 2],
                    16, 0, 0);
            }
        } else {
            #pragma unroll
            for (int i = 0; i < 6; ++i) {
                int f  = tid + i * 256;
                int r  = f >> 4;
                int c4 = (f & 15) << 2;
                int t  = t0 - PAD + r;
                float4 v = make_float4(0.f, 0.f, 0.f, 0.f);
                if ((unsigned)t < (unsigned)TDIM)
                    v = *reinterpret_cast<const float4*>(xb + (size_t)t * CC + c4);
                *reinterpret_cast<float4*>(&xs[buf][f << 2]) = v;
            }
        }
    };

    auto softmax_to_lds = [&](int buf, float* v) {
        float m = v[0];
        #pragma unroll
        for (int j = 1; j < 8; ++j) m = fmaxf(m, v[j]);
        m = fmaxf(m, __shfl_xor(m, 1, 4));
        m = fmaxf(m, __shfl_xor(m, 2, 4));
        float s = 0.f;
        #pragma unroll
        for (int j = 0; j < 8; ++j) { v[j] = __expf(v[j] - m); s += v[j]; }
        s += __shfl_xor(s, 1, 4);
        s += __shfl_xor(s, 2, 4);
        float inv = 1.f / s;
        #pragma unroll
        for (int j = 0; j < 8; ++j)
            if (fbase + j < 32)
                ws[buf][frow * WSTRIDE + fbase + j] = v[j] * inv;  // tap 31 -> 0
    };

    float4 bias4 = *reinterpret_cast<const float4*>(bg + h * SS + sq);

    auto compute_store = [&](int b, int buf) {
        float4 xw[35];
        #pragma unroll
        for (int j = 0; j < 35; ++j)
            xw[j] = *reinterpret_cast<const float4*>(&xs[buf][(tb + j) * SS + sq]);

        float4 acc[4];
        #pragma unroll
        for (int tt = 0; tt < 4; ++tt) acc[tt] = bias4;

        #pragma unroll
        for (int tt = 0; tt < 4; ++tt) {
            #pragma unroll
            for (int kq = 0; kq < 8; ++kq) {
                float4 w4 = *reinterpret_cast<const float4*>(
                    &ws[buf][(tb + tt) * WSTRIDE + (kq << 2)]);
                const float* wv = &w4.x;
                #pragma unroll
                for (int m = 0; m < 4; ++m) {
                    float w = wv[m];
                    float4 xv = xw[tt + (kq << 2) + m];
                    acc[tt].x = fmaf(w, xv.x, acc[tt].x);
                    acc[tt].y = fmaf(w, xv.y, acc[tt].y);
                    acc[tt].z = fmaf(w, xv.z, acc[tt].z);
                    acc[tt].w = fmaf(w, xv.w, acc[tt].w);
                }
            }
        }

        float* ob = og + (size_t)(b * TDIM + t0) * CC + h * SS;
        #pragma unroll
        for (int tt = 0; tt < 4; ++tt)
            *reinterpret_cast<float4*>(ob + (size_t)(tb + tt) * CC + sq) = acc[tt];
    };

    const int b1 = b0 + 4;
    float fr0[8], fr1[8];

    // prologue: filters first (waited by softmax at vmcnt(6), leaving DMA in flight)
    load_filters(b0, fr0);
    stage(b0, 0);

    // ---- tile 0 ----
    softmax_to_lds(0, fr0);
    __syncthreads();               // drains tile-0 DMA + ws[0] writes
    stage(b1, 1);                  // tile-1 DMA in flight across tile-0 compute
    load_filters(b1, fr1);
    compute_store(b0, 0);

    // ---- tile 1 ----
    softmax_to_lds(1, fr1);        // filter-load wait happens here, ~1 us after issue
    __syncthreads();               // drains tile-1 DMA + ws[1] writes
    compute_store(b1, 1);
}

extern "C" void kernel_launch(void* const* d_in, const int* in_sizes, int n_in,
                              void* d_out, int out_size, void* d_ws, size_t ws_size,
                              hipStream_t stream)
{
    const float* x    = (const float*)d_in[0];
    const float* f    = (const float*)d_in[1];
    const float* bias = (const float*)d_in[2];
    float* out        = (float*)d_out;
    lightconv_kernel<<<dim3(NBLK), 256, 0, stream>>>(x, f, bias, out);
}